// Round 1
// baseline (116.103 us; speedup 1.0000x reference)
//
#include <hip/hip_runtime.h>
#include <hip/hip_bf16.h>
#include <math.h>

typedef _Float16 f16x8 __attribute__((ext_vector_type(8)));
typedef _Float16 f16x4 __attribute__((ext_vector_type(4)));
typedef float    f32x4 __attribute__((ext_vector_type(4)));

__device__ __forceinline__ float ldin(const void* p, int i, int f32f) {
  return f32f ? ((const float*)p)[i]
              : __bfloat162float(((const __hip_bfloat16*)p)[i]);
}

__device__ __forceinline__ f32x4 MFMA(f16x8 a, f16x8 b, f32x4 c) {
  return __builtin_amdgcn_mfma_f32_16x16x32_f16(a, b, c, 0, 0, 0);
}

__device__ __forceinline__ float tanh_fast(float x) {
  float e = __expf(2.f * x);
  return 1.f - 2.f * __builtin_amdgcn_rcpf(e + 1.f);
}

__device__ __forceinline__ float redq(float v) {
  v += __shfl_xor(v, 16, 64);
  v += __shfl_xor(v, 32, 64);
  return v;
}

// fragment-linear index: (h,k) -> slot; A/B-frag reads lane-contiguous 16B.
// lane = ((k>>3)&3)*16 + (h&15), element j = k&7, tile = h>>4, k-half = k>>5.
__device__ __forceinline__ int widx(int h, int k) {
  return ((h >> 4) << 10) + ((k >> 5) << 9) + (((k >> 3) & 3) << 7) + ((h & 15) << 3) + (k & 7);
}

// ---- LDS weight panel offsets (f16 units) ----
#define OFF_W2V   0
#define OFF_W2VT  4096
#define OFF_W2H   8192
#define OFF_W2HT  12288
#define OFF_W3H   16384
#define OFF_W3HT  20480
#define OFF_W1V   24576   // packed l1 A-frags: per ht 64 lanes x 8 (q0=Whi,q1=Whi,q2=Wlo|0,q3=0)
#define OFF_W1H   26624
#define SW_N      28672

// ---- f32 constants in LDS ----
#define C_WGV0 0
#define C_WGV1 64
#define C_WGH0 128
#define C_WGH1 192
#define C_VB1  256
#define C_VB2  320
#define C_HB1  384
#define C_HB2  448
#define C_HB3  512
#define C_W4   576
#define C_K    640
#define C_HB4  656
#define C_N    660

// ===========================================================================
// Single fused kernel: 256 blocks x 512 thr. Each block preps all weight
// panels (fwd + transposed, fragment-linear) + constants into LDS (no ws, no
// prep kernel, no grid-wide dependency). Each WAVE owns 16 elements and all
// 64 h-rows, so every GEMM stage is wave-local: activation LDS round-trips
// need no barrier (DS ops are in-order per wave). 3 barriers total.
// Layer-1 packs Whi/Whi/Wlo into K-slots of ONE MFMA per tile.
// QP tail: waves 0,1 (128 lanes = 128 elems) run the Schur ADMM.
// ===========================================================================
__global__ __launch_bounds__(512, 2) void fused_kernel(
    const void* px, const void* pVW1, const void* pVb1, const void* pVW2, const void* pVb2,
    const void* pHW1, const void* pHb1, const void* pHW2, const void* pHb2,
    const void* pHW3, const void* pHb3, const void* pHW4, const void* pHb4,
    const void* pG0, const void* pK, float* out)
{
  __shared__ __align__(16) _Float16 sW[SW_N];
  __shared__ __align__(16) _Float16 sAct[16][1024];   // 2 ping-pong bufs per wave
  __shared__ __align__(16) float sQPs[128][12];
  __shared__ __align__(16) float sC[C_N];
  __shared__ int sCnt;

  const int tid = threadIdx.x;
  if (tid == 0) sCnt = 0;
  __syncthreads();
  {
    const unsigned short* xbp = (const unsigned short*)px;
    int good = 0;
#pragma unroll
    for (int i = 0; i < 2; ++i) {
      int ex = (xbp[tid * 2 + i] >> 7) & 0xFF;
      good += (ex >= 97 && ex <= 157) ? 1 : 0;
    }
    atomicAdd(&sCnt, good);
  }
  __syncthreads();
  const int f32f = (sCnt >= 870) ? 0 : 1;   // >=85% of 1024 sane -> bf16 inputs

  // ---- per-block weight prep into LDS ----
  {
    const int h = tid >> 3, k0 = (tid & 7) * 8;   // tid*8 = h*64 + k0
    auto prepM = [&](const void* src, int offF, int offT) {
      f16x8 vv;
#pragma unroll
      for (int j = 0; j < 8; ++j) vv[j] = (_Float16)ldin(src, tid * 8 + j, f32f);
      *(f16x8*)(sW + offF + widx(h, k0)) = vv;     // widx consecutive over j (k&7)
#pragma unroll
      for (int j = 0; j < 8; ++j) sW[offT + widx(k0 + j, h)] = vv[j];
    };
    prepM(pVW2, OFF_W2V, OFF_W2VT);
    prepM(pHW2, OFF_W2H, OFF_W2HT);
    prepM(pHW3, OFF_W3H, OFF_W3HT);

    if (tid < 64) {
      const int ht = tid >> 4, mm = tid & 15;
      auto prepW1 = [&](const void* src, int off) {
        const int base = off + ht * 512 + mm * 8;
#pragma unroll
        for (int j = 0; j < 8; ++j) {
          float wv = ldin(src, tid * 8 + j, f32f);
          _Float16 hh = (_Float16)wv;
          sW[base + j]       = hh;                                    // q=0: Whi (x xh)
          sW[base + 128 + j] = hh;                                    // q=1: Whi (x xl)
          sW[base + 256 + j] = f32f ? (_Float16)(wv - (float)hh)      // q=2: Wlo (x xh)
                                    : (_Float16)0.f;
          sW[base + 384 + j] = (_Float16)0.f;                         // q=3: 0
        }
      };
      prepW1(pVW1, OFF_W1V);
      prepW1(pHW1, OFF_W1H);
      // constants: W1@G0 dot products, biases, W4
      float a0 = 0.f, a1 = 0.f, b0 = 0.f, b1 = 0.f;
#pragma unroll
      for (int nn = 0; nn < 8; ++nn) {
        float g0 = ldin(pG0, 2 * nn, f32f), g1 = ldin(pG0, 2 * nn + 1, f32f);
        float wv = ldin(pVW1, tid * 8 + nn, f32f), wh = ldin(pHW1, tid * 8 + nn, f32f);
        a0 += wv * g0; a1 += wv * g1; b0 += wh * g0; b1 += wh * g1;
      }
      sC[C_WGV0 + tid] = a0; sC[C_WGV1 + tid] = a1;
      sC[C_WGH0 + tid] = b0; sC[C_WGH1 + tid] = b1;
      sC[C_VB1 + tid] = ldin(pVb1, tid, f32f);
      sC[C_VB2 + tid] = ldin(pVb2, tid, f32f);
      sC[C_HB1 + tid] = ldin(pHb1, tid, f32f);
      sC[C_HB2 + tid] = ldin(pHb2, tid, f32f);
      sC[C_HB3 + tid] = ldin(pHb3, tid, f32f);
      sC[C_W4  + tid] = ldin(pHW4, tid, f32f);
    }
    if (tid < 16) sC[C_K + tid] = ldin(pK, tid, f32f);
    if (tid == 0) sC[C_HB4] = ldin(pHb4, 0, f32f);
  }
  __syncthreads();   // sync#1: weights + constants ready

  const int lane = tid & 63, w = tid >> 6;
  const int n = lane & 15, q = lane >> 4;
  const int e0 = blockIdx.x * 128 + w * 16;

  // x B-frag, K-packed: q0=xh, q1=xl, q2=xh, q3=0; u_nom alongside.
  float un0 = 0.f, un1 = 0.f;
  f16x8 xb;
#pragma unroll
  for (int j = 0; j < 8; ++j) {
    float xv = ldin(px, (e0 + n) * 8 + j, f32f);
    _Float16 hh = (_Float16)xv;
    float lo = xv - (float)hh;
    xb[j] = (q == 1) ? (_Float16)lo : ((q == 3) ? (_Float16)0.f : hh);
    un0 -= xv * sC[C_K + 2 * j];
    un1 -= xv * sC[C_K + 2 * j + 1];
  }

  _Float16* buf0 = sAct[w * 2];
  _Float16* buf1 = sAct[w * 2 + 1];

  auto gemm64 = [&](int poff, const _Float16* b, f32x4* acc) {
    f16x8 b0 = *(const f16x8*)(b + lane * 8);
    f16x8 b1 = *(const f16x8*)(b + 512 + lane * 8);
#pragma unroll
    for (int ht = 0; ht < 4; ++ht) {
      const _Float16* ap = sW + poff + ht * 1024 + lane * 8;
      f32x4 c = {0.f, 0.f, 0.f, 0.f};
      c = MFMA(*(const f16x8*)ap, b0, c);
      c = MFMA(*(const f16x8*)(ap + 512), b1, c);
      acc[ht] = c;
    }
  };
  auto l1gemm = [&](int off, f32x4* acc) {
#pragma unroll
    for (int ht = 0; ht < 4; ++ht) {
      const _Float16* ap = sW + off + ht * 512 + lane * 8;
      f32x4 c = {0.f, 0.f, 0.f, 0.f};
      acc[ht] = MFMA(*(const f16x8*)ap, xb, c);   // Whi*xh + Whi*xl + Wlo*xh in one MFMA
    }
  };
  auto wst = [&](const f32x4* vals, _Float16* b) {
#pragma unroll
    for (int ht = 0; ht < 4; ++ht) {
      int aw = ((ht >> 1) << 9) + (((ht & 1) * 2 + (q >> 1)) << 7) + n * 8 + ((q & 1) << 2);
      f16x4 vh;
#pragma unroll
      for (int r = 0; r < 4; ++r) vh[r] = (_Float16)vals[ht][r];
      *(f16x4*)(b + aw) = vh;
    }
  };

  f32x4 acc[4], tv[4];

  // ===== V net =====
  f32x4 z1V[4], d1V[4];
  l1gemm(OFF_W1V, acc);
#pragma unroll
  for (int ht = 0; ht < 4; ++ht) {
    int hb = ht * 16 + q * 4;
    f32x4 bb = *(const f32x4*)&sC[C_VB1 + hb];
    z1V[ht] = acc[ht];
#pragma unroll
    for (int r = 0; r < 4; ++r) {
      float t = tanh_fast(z1V[ht][r] + bb[r]);
      tv[ht][r] = t; d1V[ht][r] = 1.f - t * t;
    }
  }
  wst(tv, buf0);

  gemm64(OFF_W2V, buf0, acc);
  float pV = 0.f;
#pragma unroll
  for (int ht = 0; ht < 4; ++ht) {
    int hb = ht * 16 + q * 4;
    f32x4 bb = *(const f32x4*)&sC[C_VB2 + hb];
#pragma unroll
    for (int r = 0; r < 4; ++r) {
      float t = tanh_fast(acc[ht][r] + bb[r]);
      pV += t * t;
      tv[ht][r] = t * (1.f - t * t);          // t2 * d2
    }
  }
  wst(tv, buf1);

  gemm64(OFF_W2VT, buf1, acc);
  float pgvx = 0.f, plv0 = 0.f, plv1 = 0.f;
#pragma unroll
  for (int ht = 0; ht < 4; ++ht) {
    int hb = ht * 16 + q * 4;
    f32x4 g0 = *(const f32x4*)&sC[C_WGV0 + hb];
    f32x4 g1 = *(const f32x4*)&sC[C_WGV1 + hb];
#pragma unroll
    for (int r = 0; r < 4; ++r) {
      float wt = acc[ht][r] * d1V[ht][r];
      pgvx += wt * z1V[ht][r];
      plv0 += wt * g0[r]; plv1 += wt * g1[r];
    }
  }

  // ===== H net =====
  f32x4 z1H[4], d1H[4], d2H[4];
  l1gemm(OFF_W1H, acc);
#pragma unroll
  for (int ht = 0; ht < 4; ++ht) {
    int hb = ht * 16 + q * 4;
    f32x4 bb = *(const f32x4*)&sC[C_HB1 + hb];
    z1H[ht] = acc[ht];
#pragma unroll
    for (int r = 0; r < 4; ++r) {
      float t = tanh_fast(z1H[ht][r] + bb[r]);
      tv[ht][r] = t; d1H[ht][r] = 1.f - t * t;
    }
  }
  wst(tv, buf0);

  gemm64(OFF_W2H, buf0, acc);
#pragma unroll
  for (int ht = 0; ht < 4; ++ht) {
    int hb = ht * 16 + q * 4;
    f32x4 bb = *(const f32x4*)&sC[C_HB2 + hb];
#pragma unroll
    for (int r = 0; r < 4; ++r) {
      float t = tanh_fast(acc[ht][r] + bb[r]);
      tv[ht][r] = t; d2H[ht][r] = 1.f - t * t;
    }
  }
  wst(tv, buf1);

  gemm64(OFF_W3H, buf1, acc);
  float pH = 0.f;
#pragma unroll
  for (int ht = 0; ht < 4; ++ht) {
    int hb = ht * 16 + q * 4;
    f32x4 bb = *(const f32x4*)&sC[C_HB3 + hb];
    f32x4 w4 = *(const f32x4*)&sC[C_W4 + hb];
#pragma unroll
    for (int r = 0; r < 4; ++r) {
      float t = tanh_fast(acc[ht][r] + bb[r]);
      pH += t * w4[r];
      tv[ht][r] = w4[r] * (1.f - t * t);      // v4
    }
  }
  wst(tv, buf0);

  gemm64(OFF_W3HT, buf0, acc);                // v3
#pragma unroll
  for (int ht = 0; ht < 4; ++ht)
#pragma unroll
    for (int r = 0; r < 4; ++r) tv[ht][r] = acc[ht][r] * d2H[ht][r];   // bb
  wst(tv, buf1);

  gemm64(OFF_W2HT, buf1, acc);                // v2
  float pghx = 0.f, plh0 = 0.f, plh1 = 0.f;
#pragma unroll
  for (int ht = 0; ht < 4; ++ht) {
    int hb = ht * 16 + q * 4;
    f32x4 g0 = *(const f32x4*)&sC[C_WGH0 + hb];
    f32x4 g1 = *(const f32x4*)&sC[C_WGH1 + hb];
#pragma unroll
    for (int r = 0; r < 4; ++r) {
      float wt = acc[ht][r] * d1H[ht][r];
      pghx += wt * z1H[ht][r];
      plh0 += wt * g0[r]; plh1 += wt * g1[r];
    }
  }

  // ---- per-element scalars (reduce over q; this wave owns all 64 h) ----
  {
    float a0 = redq(plh0), a1 = redq(plh1), a2 = redq(plv0), a3 = redq(plv1);
    float a4 = redq(pghx), a5 = redq(pgvx), a6 = redq(pV), a7 = redq(pH);
    if (q == 0) {
      float* sp = sQPs[w * 16 + n];
      sp[0] = a0; sp[1] = a1; sp[2] = a2; sp[3] = a3;
      sp[4] = a4; sp[5] = a5; sp[6] = a6; sp[7] = a7;
      sp[8] = un0; sp[9] = un1;
    }
  }
  __syncthreads();   // sync#2: scalars ready

  // ====== QP tail: waves 0,1 (128 lanes = 128 elems), Schur ADMM ======
  if (tid >= 128) return;
  const int e = blockIdx.x * 128 + tid;
  const float* sp = sQPs[tid];
  float gh0 = sp[0], gh1 = sp[1], gv0 = sp[2], gv1 = sp[3];
  float ghx = sp[4], gvx = sp[5];
  float V = 0.5f * sp[6];
  float H = sp[7] + sC[C_HB4];
  un0 = sp[8]; un1 = sp[9];
  out[98304 + e]  = V;
  out[163840 + e] = H;

  const float im = 1.0f / 1.2f;
  const float sg = 1e-6f;

  float lo0 = ghx - H;
  float hi1 = gvx - V;
  float lo2 = ghx * im - H;
  float hi3 = gvx * im - V;
  float qv0 = -2.f * un0, qv1 = -2.f * un1;

  const float d  = 2.f + sg;
  const float rd = 1.f / d;
  const float al = 1.f + im * im;
  const float be = al * (1.f - rd);
  float S00 = be * (gh0 * gh0 + gv0 * gv0) + d;
  float S11 = be * (gh1 * gh1 + gv1 * gv1) + d;
  float S01 = be * (gh0 * gh1 + gv0 * gv1);
  float idet = 1.f / (S00 * S11 - S01 * S01);
  float i00 = S11 * idet, i11 = S00 * idet, i01 = -S01 * idet;

  float X0 = 0.f, X1 = 0.f, X2 = 0.f, X3 = 0.f, X4 = 0.f, X5 = 0.f;
  float Z[8] = {0.f, 0.f, 0.f, 0.f, 0.f, 0.f, 0.f, 0.f};
  float Y[8] = {0.f, 0.f, 0.f, 0.f, 0.f, 0.f, 0.f, 0.f};

#pragma unroll 1
  for (int it = 0; it < 80; ++it) {
    float t0 = Z[0] - Y[0], t1 = Z[1] - Y[1], t2 = Z[2] - Y[2], t3 = Z[3] - Y[3];
    float t4 = Z[4] - Y[4], t5 = Z[5] - Y[5], t6 = Z[6] - Y[6], t7 = Z[7] - Y[7];
    float tauh = t0 + im * t2, tauv = t1 + im * t3;
    float b0 = sg * X0 - qv0 + gh0 * tauh + gv0 * tauv;
    float b1 = sg * X1 - qv1 + gh1 * tauh + gv1 * tauv;
    float b2 = sg * X2 - 100.f - t1 + t4;
    float b3 = sg * X3 - 100.f - t3 + t5;
    float b4 = sg * X4 - 50.f + t0 + t6;
    float b5 = sg * X5 - 50.f + t2 + t7;
    float pp = b2 + im * b3;
    float s2 = b4 + im * b5;
    float cb0 = gh0 * s2 - gv0 * pp;
    float cb1 = gh1 * s2 - gv1 * pp;
    float u0b = b0 - cb0 * rd;
    float u1b = b1 - cb1 * rd;
    X0 = i00 * u0b + i01 * u1b;
    X1 = i01 * u0b + i11 * u1b;
    float gdH = gh0 * X0 + gh1 * X1;
    float gdV = gv0 * X0 + gv1 * X1;
    X2 = (b2 + gdV) * rd;
    X3 = (b3 + im * gdV) * rd;
    X4 = (b4 - gdH) * rd;
    X5 = (b5 - im * gdH) * rd;
    float zt0 = gdH + X4;
    float zt1 = gdV - X2;
    float zt2 = gdH * im + X5;
    float zt3 = gdV * im - X3;

    float v, zn;
    v = zt0 + Y[0]; zn = fmaxf(v, lo0); Y[0] += zt0 - zn; Z[0] = zn;
    v = zt1 + Y[1]; zn = fminf(v, hi1); Y[1] += zt1 - zn; Z[1] = zn;
    v = zt2 + Y[2]; zn = fmaxf(v, lo2); Y[2] += zt2 - zn; Z[2] = zn;
    v = zt3 + Y[3]; zn = fminf(v, hi3); Y[3] += zt3 - zn; Z[3] = zn;
    v = X2 + Y[4];  zn = fmaxf(v, 0.f); Y[4] += X2 - zn;  Z[4] = zn;
    v = X3 + Y[5];  zn = fmaxf(v, 0.f); Y[5] += X3 - zn;  Z[5] = zn;
    v = X4 + Y[6];  zn = fmaxf(v, 0.f); Y[6] += X4 - zn;  Z[6] = zn;
    v = X5 + Y[7];  zn = fmaxf(v, 0.f); Y[7] += X5 - zn;  Z[7] = zn;
  }

  float relax = 0.5f * (X2 + X3);
  const float cc = 0.5f * (1.f + im);
  float Vdot = cc * (gv0 * X0 + gv1 * X1 - gvx);
  float Hdot = cc * (gh0 * X0 + gh1 * X1 - ghx);

  out[2 * e]      = X0;
  out[2 * e + 1]  = X1;
  out[65536 + e]  = relax;
  out[131072 + e] = Vdot;
  out[196608 + e] = Hdot;
}

extern "C" void kernel_launch(void* const* d_in, const int* in_sizes, int n_in,
                              void* d_out, int out_size, void* d_ws, size_t ws_size,
                              hipStream_t stream) {
  (void)d_ws; (void)ws_size; (void)in_sizes; (void)n_in; (void)out_size;
  fused_kernel<<<256, 512, 0, stream>>>(
      d_in[0], d_in[1], d_in[2], d_in[3], d_in[4], d_in[5], d_in[6],
      d_in[7], d_in[8], d_in[9], d_in[10], d_in[11], d_in[12],
      d_in[13], d_in[14], (float*)d_out);
}